// Round 14
// baseline (234.850 us; speedup 1.0000x reference)
//
#include <hip/hip_runtime.h>
#include <stdint.h>

typedef short bh8 __attribute__((ext_vector_type(8)));   // 8 bf16 (4 VGPR)
typedef float f32x4 __attribute__((ext_vector_type(4))); // MFMA accumulator

// counts is padded: one counter per 64B cacheline -> counts[d * 16]
#define CPAD 16
// edges per thread for hist/scatter grid-stride (8 independent chains in flight)
#define HEPT 8
// nodes per wave in agg kernels (4 independent setup chains hoisted)
#define NPW 4

// ---------- helpers ----------
__device__ __forceinline__ float b2f(unsigned short u) {
    return __uint_as_float(((unsigned int)u) << 16);
}
__device__ __forceinline__ unsigned short f2b(float f) {
    unsigned int x = __float_as_uint(f);
    return (unsigned short)((x + 0x7FFFu + ((x >> 16) & 1u)) >> 16);  // RNE
}
__device__ __forceinline__ float ldf(const void* p, size_t i, int bf) {
    return bf ? b2f(((const unsigned short*)p)[i]) : ((const float*)p)[i];
}
__device__ __forceinline__ int ldi(const int* p, size_t i, int i64f) {
    return i64f ? p[2 * i] : p[i];
}
__device__ __forceinline__ bh8 zero8() {
    bh8 z;
    z[0]=z[1]=z[2]=z[3]=z[4]=z[5]=z[6]=z[7]=0;
    return z;
}
// x-row fragment: 8 bf16 at (row, col..col+8); converts on the fly for f32 input
__device__ __forceinline__ bh8 ld_xfrag(const void* xr, int bf, size_t row, int col) {
    if (bf) {
        return *(const bh8*)((const unsigned short*)xr + row * 128 + col);
    } else {
        const float* xp = (const float*)xr + row * 128 + col;
        float4 a = *(const float4*)xp;
        float4 b = *(const float4*)(xp + 4);
        bh8 r;
        r[0] = (short)f2b(a.x); r[1] = (short)f2b(a.y);
        r[2] = (short)f2b(a.z); r[3] = (short)f2b(a.w);
        r[4] = (short)f2b(b.x); r[5] = (short)f2b(b.y);
        r[6] = (short)f2b(b.z); r[7] = (short)f2b(b.w);
        return r;
    }
}

// ---------- K1: prep (self-detect) + detect->flags + zero padded counts + state ----------
// blocks [0,32): Wt1 | [32,48): Wt2 | [48]: detect flags | [49,49+NZ): zero counts
// last block: zero scan state
__global__ void k_prep2(const void* __restrict__ W1, unsigned short* __restrict__ Wt1,
                        const void* __restrict__ W2, unsigned short* __restrict__ Wt2,
                        const unsigned short* __restrict__ xs, const int* __restrict__ ei32,
                        int* __restrict__ flags, int* __restrict__ counts,
                        int* __restrict__ done, int N, int NZ) {
    int blk = blockIdx.x, t = threadIdx.x;
    if (blk < 48) {
        // self-detect bf16-vs-f32 (same heuristic as detect block)
        __shared__ int bad;
        if (t == 0) bad = 0;
        __syncthreads();
        int b = 0;
        for (int i = t; i < 4096; i += 256) {
            unsigned e = (xs[i] >> 7) & 0xFF;
            if (e >= 0xE2) b = 1;
        }
        if (b) atomicOr(&bad, 1);
        __syncthreads();
        int bf = bad ? 0 : 1;
        if (blk < 32) {
            int idx = blk * 512 + t * 2;
            #pragma unroll
            for (int j = 0; j < 2; j++, idx++) {      // Wt1[n][k] = W1[k][n], 128x128
                int k = idx >> 7, nn = idx & 127;
                Wt1[nn * 128 + k] = bf ? ((const unsigned short*)W1)[idx]
                                       : f2b(((const float*)W1)[idx]);
            }
        } else {
            int idx = (blk - 32) * 512 + t * 2;
            #pragma unroll
            for (int j = 0; j < 2; j++, idx++) {      // Wt2[n][k] = W2[k][n], k<128,n<64
                int k = idx >> 6, nn = idx & 63;
                Wt2[nn * 128 + k] = bf ? ((const unsigned short*)W2)[idx]
                                       : f2b(((const float*)W2)[idx]);
            }
        }
        return;
    }
    if (blk == 48) {                                   // flags for downstream kernels
        __shared__ int bad, nz;
        if (t == 0) { bad = 0; nz = 0; }
        __syncthreads();
        int b = 0;
        for (int i = t; i < 4096; i += 256) {
            unsigned e = (xs[i] >> 7) & 0xFF;
            if (e >= 0xE2) b = 1;
        }
        if (b) atomicOr(&bad, 1);
        int n = 0;
        for (int i = t; i < 512; i += 256) {
            if (ei32[2 * i + 1] != 0) n = 1;
        }
        if (n) atomicOr(&nz, 1);
        __syncthreads();
        if (t == 0) { flags[0] = bad ? 0 : 1; flags[1] = nz ? 0 : 1; }
        return;
    }
    int zb = blk - 49;
    if (zb < NZ) {                                     // zero padded counts (N*CPAD ints)
        int NT = N * CPAD;
        int base = zb * 1024 + t * 4;
        #pragma unroll
        for (int j = 0; j < 4; j++)
            if (base + j < NT) counts[base + j] = 0;
        return;
    }
    if (t == 0) done[0] = 0;                           // zero scan state
}

// ---------- K2: hist grid-stride (blocks < HB2)  ||  layer-1 GEMM (R5 shape) ----------
__global__ __launch_bounds__(256)
void k_hist_gemm1(const int* __restrict__ ei, int* __restrict__ counts,
                  int* __restrict__ eoff,
                  const void* __restrict__ xr, const unsigned short* __restrict__ Wt,
                  const void* __restrict__ aSr, const void* __restrict__ aDr,
                  unsigned int* __restrict__ xh1b, float* __restrict__ a_src,
                  float* __restrict__ a_dst, const int* __restrict__ flags,
                  int E, int Et, int HB2, int N) {
    __shared__ unsigned short Wl[128 * 136];   // +8 pad: 2-way bank alias (free)
    __shared__ float aSf[128], aDf[128];
    if ((int)blockIdx.x < HB2) {              // -------- histogram path --------
        int i64f = flags[1];
        int ebase = blockIdx.x * (256 * HEPT) + threadIdx.x;
        #pragma unroll
        for (int j = 0; j < HEPT; j++) {
            int e = ebase + j * 256;
            if (e < Et) {
                int d = (e < E) ? ldi(ei, (size_t)E + e, i64f) : (e - E);
                eoff[e] = atomicAdd(&counts[(size_t)d * CPAD], 1);
            }
        }
        return;
    }
    // -------- GEMM path: D' = Wt1 x^T --------
    int t = threadIdx.x;
    int bf = flags[0];
    int r0 = ((int)blockIdx.x - HB2) * 64;
    if (t < 128) { aSf[t] = ldf(aSr, t, bf); aDf[t] = ldf(aDr, t, bf); }
    #pragma unroll
    for (int i = 0; i < 8; i++) {             // Wt1: 2048 uint4, coalesced stage
        int idx = t + 256 * i;
        int row = idx >> 4, c16 = idx & 15;
        *(uint4*)&Wl[row * 136 + c16 * 8] = ((const uint4*)Wt)[idx];
    }
    __syncthreads();
    int w = t >> 6, lane = t & 63;
    int m16 = lane & 15, quad = lane >> 4;
    int node = r0 + w * 16 + m16;
    bool valid = node < N;
    f32x4 acc[8];
    #pragma unroll
    for (int ct = 0; ct < 8; ct++) acc[ct] = (f32x4){0.f, 0.f, 0.f, 0.f};
    #pragma unroll
    for (int kb = 0; kb < 4; kb++) {
        int col = kb * 32 + quad * 8;
        bh8 xf = valid ? ld_xfrag(xr, bf, (size_t)node, col) : zero8();
        #pragma unroll
        for (int ct = 0; ct < 8; ct++) {
            bh8 wf = *(const bh8*)&Wl[(ct * 16 + m16) * 136 + col];
            acc[ct] = __builtin_amdgcn_mfma_f32_16x16x32_bf16(wf, xf, acc[ct], 0, 0, 0);
        }
    }
    // epilogue from acc: ch = ct*16 + quad*4 + r, head h == ct (16 ch/head)
    #pragma unroll
    for (int ct = 0; ct < 8; ct++) {
        float s = 0.f, d = 0.f;
        #pragma unroll
        for (int r = 0; r < 4; r++) {
            int ch = ct * 16 + quad * 4 + r;
            s += acc[ct][r] * aSf[ch];
            d += acc[ct][r] * aDf[ch];
        }
        s += __shfl_xor(s, 16); s += __shfl_xor(s, 32);
        d += __shfl_xor(d, 16); d += __shfl_xor(d, 32);
        if (valid) {
            if (quad == 0) {
                a_src[(size_t)node * 8 + ct] = s;
                a_dst[(size_t)node * 8 + ct] = d;
            }
            uint2 pk;
            pk.x = (unsigned int)f2b(acc[ct][0]) | ((unsigned int)f2b(acc[ct][1]) << 16);
            pk.y = (unsigned int)f2b(acc[ct][2]) | ((unsigned int)f2b(acc[ct][3]) << 16);
            *(uint2*)&xh1b[(size_t)node * 64 + ct * 8 + quad * 2] = pk;
        }
    }
}

// ---------- K3: single-pass scan over padded counts ----------
__global__ __launch_bounds__(256)
void k_scan(const int* __restrict__ counts, int* __restrict__ rowptr,
            int* __restrict__ bsums, int* __restrict__ done,
            int N, int Et, int NB) {
    __shared__ int sd[256];
    int t = threadIdx.x, b = blockIdx.x;
    int base = b * 1024 + t * 4;
    int v0 = (base + 0 < N) ? counts[(size_t)(base + 0) * CPAD] : 0;
    int v1 = (base + 1 < N) ? counts[(size_t)(base + 1) * CPAD] : 0;
    int v2 = (base + 2 < N) ? counts[(size_t)(base + 2) * CPAD] : 0;
    int v3 = (base + 3 < N) ? counts[(size_t)(base + 3) * CPAD] : 0;
    int ls = v0 + v1 + v2 + v3;
    sd[t] = ls; __syncthreads();
    for (int off = 1; off < 256; off <<= 1) {
        int x = 0;
        if (t >= off) x = sd[t - off];
        __syncthreads();
        if (t >= off) sd[t] += x;
        __syncthreads();
    }
    int incl = sd[t];
    int ex = incl - ls;
    if (t == 255) {                            // publish block total, bump done
        bsums[b] = incl;
        __threadfence();
        atomicAdd(done, 1);
    }
    if (t == 0) {                              // wait for all publishers
        while (atomicAdd(done, 0) < NB) __builtin_amdgcn_s_sleep(1);
    }
    __syncthreads();
    __threadfence();
    int contrib = (t < b) ? atomicAdd(&bsums[t], 0) : 0;   // parallel lookback reads
    sd[t] = contrib; __syncthreads();
    for (int o = 128; o > 0; o >>= 1) {        // tree-reduce predecessors' totals
        if (t < o) sd[t] += sd[t + o];
        __syncthreads();
    }
    int off2 = sd[0];
    if (base + 0 < N) rowptr[base + 0] = ex + off2; ex += v0;
    if (base + 1 < N) rowptr[base + 1] = ex + off2; ex += v1;
    if (base + 2 < N) rowptr[base + 2] = ex + off2; ex += v2;
    if (base + 3 < N) rowptr[base + 3] = ex + off2;
    if (b == NB - 1 && t == 255) rowptr[N] = Et;
}

// ---------- scatter (atomic-free, grid-stride HEPT for pipelined chains) ----------
__global__ void k_scatter(const int* __restrict__ ei, const int* __restrict__ rowptr,
                          const int* __restrict__ eoff, int* __restrict__ esrc,
                          const int* __restrict__ flags, int E, int Et) {
    int i64f = flags[1];
    int ebase = blockIdx.x * (256 * HEPT) + threadIdx.x;
    #pragma unroll
    for (int j = 0; j < HEPT; j++) {
        int e = ebase + j * 256;
        if (e < Et) {
            int s, d;
            if (e < E) { s = ldi(ei, (size_t)e, i64f); d = ldi(ei, (size_t)E + e, i64f); }
            else       { s = d = e - E; }
            esrc[rowptr[d] + eoff[e]] = s;
        }
    }
}

// ---------- layer 1 softmax-aggregate: NPW nodes/wave, setup chains hoisted ----------
// All NPW nodes' rowptr->esrc->a_src dependent chains issue before any edge loop
// runs: ~20 independent loads in flight hide the ~1500cy setup latency.
__global__ __launch_bounds__(256)
void k_agg1(const int* __restrict__ rowptr, const int* __restrict__ esrc,
            const float* __restrict__ a_src, const float* __restrict__ a_dst,
            const unsigned int* __restrict__ xh1b, const void* __restrict__ b1,
            unsigned int* __restrict__ h1b, const int* __restrict__ flags, int N) {
    int grp = blockIdx.x * 4 + (threadIdx.x >> 6);
    int lane = threadIdx.x & 63;
    int bf = flags[0];
    int h8 = lane & 7;
    int q  = lane >> 3;
    float bia0 = ldf(b1, 2 * lane, bf);
    float bia1 = ldf(b1, 2 * lane + 1, bf);
    int   R0[NPW], R1[NPW], SN[NPW];
    float AD[NPW], AN[NPW];
    #pragma unroll
    for (int k = 0; k < NPW; k++) {            // hoisted: rowptr + a_dst, all nodes
        int node = grp * NPW + k;
        bool v = node < N;
        R0[k] = v ? rowptr[node] : 0;
        R1[k] = v ? rowptr[node + 1] : 0;
        AD[k] = v ? a_dst[(size_t)node * 8 + h8] : 0.f;
    }
    #pragma unroll
    for (int k = 0; k < NPW; k++) {            // hoisted: first esrc + a_src, all nodes
        int pidx = R0[k] + q;
        bool pval = pidx < R1[k];
        int s = pval ? esrc[pidx] : 0;
        SN[k] = s;
        AN[k] = pval ? a_src[(size_t)s * 8 + h8] : 0.f;
    }
    #pragma unroll
    for (int k = 0; k < NPW; k++) {
        int node = grp * NPW + k;
        if (node >= N) continue;               // wave-uniform
        int r0 = R0[k], r1 = R1[k];
        float adst = AD[k];
        int   s_next = SN[k];
        float a_next = AN[k];
        float den = 0.f, acc0 = 0.f, acc1 = 0.f;
        for (int e = r0; e < r1; e += 8) {
            int   s_mine = s_next;
            float a_cur  = a_next;
            bool  vcur   = (e + q) < r1;
            int idx2 = e + 8 + q;
            bool v2 = idx2 < r1;
            s_next = v2 ? esrc[idx2] : 0;
            a_next = v2 ? a_src[(size_t)s_next * 8 + h8] : 0.f;
            float v = a_cur + adst;
            v = v > 0.f ? v : 0.2f * v;
            float ex = vcur ? __expf(v) : 0.f;
            den += ex;
            #pragma unroll
            for (int q2 = 0; q2 < 8; q2++) {
                int   s_q  = __builtin_amdgcn_readlane(s_mine, q2 * 8);
                float ex_q = __shfl(ex, q2 * 8 + q);
                const unsigned int* rowp = xh1b + (size_t)s_q * 64;
                unsigned int wv = rowp[lane];
                acc0 += ex_q * b2f((unsigned short)wv);
                acc1 += ex_q * b2f((unsigned short)(wv >> 16));
            }
        }
        den += __shfl_xor(den, 8);
        den += __shfl_xor(den, 16);
        den += __shfl_xor(den, 32);
        float dA = __shfl(den, q) + 1e-16f;
        float o0 = acc0 / dA + bia0;
        float o1 = acc1 / dA + bia1;
        o0 = o0 > 0.f ? o0 : expm1f(o0);
        o1 = o1 > 0.f ? o1 : expm1f(o1);
        h1b[(size_t)node * 64 + lane] =
            (unsigned int)f2b(o0) | ((unsigned int)f2b(o1) << 16);
    }
}

// ---------- layer 2 GEMM, MFMA: xh2 = h1 @ W2 via D' = Wt2 h1^T; fused att2 ----------
__global__ __launch_bounds__(256)
void k_gemm2m(const unsigned int* __restrict__ h1b, const unsigned short* __restrict__ Wt2,
              const void* __restrict__ aSr, const void* __restrict__ aDr,
              unsigned int* __restrict__ xh2b, float* __restrict__ a_src,
              float* __restrict__ a_dst, const int* __restrict__ flags, int N) {
    __shared__ unsigned short Xl[64 * 136];
    __shared__ unsigned short Wl[64 * 136];
    __shared__ float aSf[64], aDf[64];
    int t = threadIdx.x;
    int bf = flags[0];
    int r0 = blockIdx.x * 64;
    if (t < 64) { aSf[t] = ldf(aSr, t, bf); aDf[t] = ldf(aDr, t, bf); }
    #pragma unroll
    for (int i = 0; i < 4; i++) {            // Wt2: 64 rows x 16 uint4 = 1024 uint4
        int idx = t + 256 * i;
        int row = idx >> 4, c16 = idx & 15;
        *(uint4*)&Wl[row * 136 + c16 * 8] = ((const uint4*)Wt2)[idx];
    }
    {
        const uint4* Xv = (const uint4*)h1b;  // bf16 rows, 16 uint4 each
        #pragma unroll
        for (int i = 0; i < 4; i++) {
            int idx = t + 256 * i;
            int row = idx >> 4, c16 = idx & 15;
            uint4 v = (r0 + row < N) ? Xv[(size_t)(r0 + row) * 16 + c16] : uint4{0,0,0,0};
            *(uint4*)&Xl[row * 136 + c16 * 8] = v;
        }
    }
    __syncthreads();
    int w = t >> 6, lane = t & 63;
    int m16 = lane & 15, quad = lane >> 4;
    f32x4 acc[4];
    #pragma unroll
    for (int ct = 0; ct < 4; ct++) acc[ct] = (f32x4){0.f, 0.f, 0.f, 0.f};
    #pragma unroll
    for (int kb = 0; kb < 4; kb++) {
        bh8 xf = *(const bh8*)&Xl[(w * 16 + m16) * 136 + kb * 32 + quad * 8];
        #pragma unroll
        for (int ct = 0; ct < 4; ct++) {
            bh8 wf = *(const bh8*)&Wl[(ct * 16 + m16) * 136 + kb * 32 + quad * 8];
            acc[ct] = __builtin_amdgcn_mfma_f32_16x16x32_bf16(wf, xf, acc[ct], 0, 0, 0);
        }
    }
    float ps = 0.f, pd = 0.f;
    #pragma unroll
    for (int ct = 0; ct < 4; ct++) {
        #pragma unroll
        for (int r = 0; r < 4; r++) {
            int ch = ct * 16 + quad * 4 + r;
            ps += acc[ct][r] * aSf[ch];
            pd += acc[ct][r] * aDf[ch];
        }
    }
    ps += __shfl_xor(ps, 16); ps += __shfl_xor(ps, 32);
    pd += __shfl_xor(pd, 16); pd += __shfl_xor(pd, 32);
    int node = r0 + w * 16 + m16;
    if (node < N) {
        if (quad == 0) { a_src[node] = ps; a_dst[node] = pd; }
        #pragma unroll
        for (int ct = 0; ct < 4; ct++) {
            uint2 pk;
            pk.x = (unsigned int)f2b(acc[ct][0]) | ((unsigned int)f2b(acc[ct][1]) << 16);
            pk.y = (unsigned int)f2b(acc[ct][2]) | ((unsigned int)f2b(acc[ct][3]) << 16);
            *(uint2*)&xh2b[(size_t)node * 32 + ct * 8 + quad * 2] = pk;
        }
    }
}

// ---------- layer 2 softmax-aggregate -> output: NPW nodes/wave, hoisted setup ----------
__global__ __launch_bounds__(256)
void k_agg2(const int* __restrict__ rowptr, const int* __restrict__ esrc,
            const float* __restrict__ a_src, const float* __restrict__ a_dst,
            const unsigned int* __restrict__ xh2b, const void* __restrict__ bias,
            void* __restrict__ out, const int* __restrict__ flags, int N) {
    int grp = blockIdx.x * 4 + (threadIdx.x >> 6);
    int lane = threadIdx.x & 63;
    int bf = flags[0];
    int q = lane >> 3;
    const unsigned short* xs = (const unsigned short*)xh2b;
    float bia = ldf(bias, lane, bf);
    int   R0[NPW], R1[NPW], SN[NPW];
    float AD[NPW], AN[NPW];
    #pragma unroll
    for (int k = 0; k < NPW; k++) {            // hoisted: rowptr + a_dst, all nodes
        int node = grp * NPW + k;
        bool v = node < N;
        R0[k] = v ? rowptr[node] : 0;
        R1[k] = v ? rowptr[node + 1] : 0;
        AD[k] = v ? a_dst[node] : 0.f;
    }
    #pragma unroll
    for (int k = 0; k < NPW; k++) {            // hoisted: first esrc + a_src, all nodes
        int pidx = R0[k] + q;
        bool pval = pidx < R1[k];
        int s = pval ? esrc[pidx] : 0;
        SN[k] = s;
        AN[k] = pval ? a_src[s] : 0.f;
    }
    #pragma unroll
    for (int k = 0; k < NPW; k++) {
        int node = grp * NPW + k;
        if (node >= N) continue;               // wave-uniform
        int r0 = R0[k], r1 = R1[k];
        float adst = AD[k];
        int   s_next = SN[k];
        float a_next = AN[k];
        float den = 0.f, acc = 0.f;
        for (int e = r0; e < r1; e += 8) {
            int   s_mine = s_next;
            float a_cur  = a_next;
            bool  vcur   = (e + q) < r1;
            int idx2 = e + 8 + q;
            bool v2 = idx2 < r1;
            s_next = v2 ? esrc[idx2] : 0;
            a_next = v2 ? a_src[s_next] : 0.f;
            float v = a_cur + adst;
            v = v > 0.f ? v : 0.2f * v;
            float ex = vcur ? __expf(v) : 0.f;
            den += ex;
            #pragma unroll
            for (int q2 = 0; q2 < 8; q2++) {
                int   s_q  = __builtin_amdgcn_readlane(s_mine, q2 * 8);
                float ex_q = __uint_as_float(
                    (unsigned int)__builtin_amdgcn_readlane(__float_as_uint(ex), q2 * 8));
                const unsigned short* rowp = xs + (size_t)s_q * 64;
                acc += ex_q * b2f(rowp[lane]);
            }
        }
        den += __shfl_xor(den, 8);
        den += __shfl_xor(den, 16);
        den += __shfl_xor(den, 32);
        float o = acc / (den + 1e-16f) + bia;
        size_t oi = (size_t)node * 64 + lane;
        if (bf) ((unsigned short*)out)[oi] = f2b(o);
        else    ((float*)out)[oi] = o;
    }
}

// ---------- launch ----------
extern "C" void kernel_launch(void* const* d_in, const int* in_sizes, int n_in,
                              void* d_out, int out_size, void* d_ws, size_t ws_size,
                              hipStream_t stream) {
    const void* x   = d_in[0];
    const int*  ei  = (const int*)d_in[1];
    const void* W1  = d_in[2];
    const void* aS1 = d_in[3];
    const void* aD1 = d_in[4];
    const void* b1  = d_in[5];
    const void* W2  = d_in[6];
    const void* aS2 = d_in[7];
    const void* aD2 = d_in[8];
    const void* b2v = d_in[9];

    const int N  = in_sizes[0] / 128;   // 50000
    const int E  = in_sizes[1] / 2;     // 800000
    const int Et = E + N;

    char* p = (char*)d_ws;
    auto alloc = [&](size_t bytes) -> char* {
        char* q = p; p += (bytes + 255) & ~(size_t)255; return q;
    };
    unsigned int* xh1b = (unsigned int*)alloc((size_t)N * 64 * 4);
    unsigned int* h1b  = (unsigned int*)alloc((size_t)N * 64 * 4);
    unsigned int* xh2b = (unsigned int*)alloc((size_t)N * 32 * 4);
    float* as1  = (float*)alloc((size_t)N * 8 * 4);
    float* ad1  = (float*)alloc((size_t)N * 8 * 4);
    float* as2  = (float*)alloc((size_t)N * 4);
    float* ad2  = (float*)alloc((size_t)N * 4);
    int* counts = (int*)alloc((size_t)N * CPAD * 4);   // padded: 1 counter / 64B line
    int* rowptr = (int*)alloc((size_t)(N + 1) * 4);
    int* eoff   = (int*)alloc((size_t)Et * 4);
    int* esrc   = (int*)alloc((size_t)Et * 4);
    int* bsums  = (int*)alloc(256 * 4);
    int* flags  = (int*)alloc(16 * 4);
    int* done   = (int*)alloc(16 * 4);
    unsigned short* Wt1 = (unsigned short*)alloc(128 * 128 * 2);
    unsigned short* Wt2 = (unsigned short*)alloc(64 * 128 * 2);

    const int NZ  = (N * CPAD + 1023) / 1024; // zero blocks for padded counts
    const int NB  = (N + 1023) / 1024;        // scan blocks (<=256 assumed)
    const int HB2 = (Et + 256 * HEPT - 1) / (256 * HEPT);  // hist/scatter blocks
    const int GT  = (N + 63) / 64;            // gemm1 tiles
    const int AB  = (N + 4 * NPW - 1) / (4 * NPW);  // agg blocks (4 waves x NPW nodes)

    // K1: W transposes + flags + zero padded counts + zero scan state
    k_prep2<<<48 + 1 + NZ + 1, 256, 0, stream>>>(W1, Wt1, W2, Wt2,
                                                 (const unsigned short*)x, ei,
                                                 flags, counts, done, N, NZ);
    // K2: histogram (grid-stride, pipelined atomics) || layer-1 GEMM (36KB LDS)
    k_hist_gemm1<<<HB2 + GT, 256, 0, stream>>>(ei, counts, eoff, x, Wt1, aS1, aD1,
                                               xh1b, as1, ad1, flags, E, Et, HB2, N);
    // K3: single-pass scan -> final rowptr
    k_scan<<<NB, 256, 0, stream>>>(counts, rowptr, bsums, done, N, Et, NB);
    // K4: scatter edges into CSR (grid-stride, pipelined chains)
    k_scatter<<<HB2, 256, 0, stream>>>(ei, rowptr, eoff, esrc, flags, E, Et);
    // K5-K7: aggregate / GEMM2 / aggregate (agg: NPW nodes/wave, hoisted setup)
    k_agg1<<<AB, 256, 0, stream>>>(rowptr, esrc, as1, ad1, xh1b, b1, h1b, flags, N);
    k_gemm2m<<<GT, 256, 0, stream>>>(h1b, Wt2, aS2, aD2, xh2b, as2, ad2, flags, N);
    k_agg2<<<AB, 256, 0, stream>>>(rowptr, esrc, as2, ad2, xh2b, b2v, d_out, flags, N);
}

// Round 15
// 226.165 us; speedup vs baseline: 1.0384x; 1.0384x over previous
//
#include <hip/hip_runtime.h>
#include <stdint.h>

typedef short bh8 __attribute__((ext_vector_type(8)));   // 8 bf16 (4 VGPR)
typedef float f32x4 __attribute__((ext_vector_type(4))); // MFMA accumulator

// counts is padded: one counter per 64B cacheline -> counts[d * 16]
#define CPAD 16
// edges per thread for hist/scatter grid-stride (8 independent chains in flight)
#define HEPT 8

// ---------- helpers ----------
__device__ __forceinline__ float b2f(unsigned short u) {
    return __uint_as_float(((unsigned int)u) << 16);
}
__device__ __forceinline__ unsigned short f2b(float f) {
    unsigned int x = __float_as_uint(f);
    return (unsigned short)((x + 0x7FFFu + ((x >> 16) & 1u)) >> 16);  // RNE
}
__device__ __forceinline__ float ldf(const void* p, size_t i, int bf) {
    return bf ? b2f(((const unsigned short*)p)[i]) : ((const float*)p)[i];
}
__device__ __forceinline__ int ldi(const int* p, size_t i, int i64f) {
    return i64f ? p[2 * i] : p[i];
}
__device__ __forceinline__ bh8 zero8() {
    bh8 z;
    z[0]=z[1]=z[2]=z[3]=z[4]=z[5]=z[6]=z[7]=0;
    return z;
}
// x-row fragment: 8 bf16 at (row, col..col+8); converts on the fly for f32 input
__device__ __forceinline__ bh8 ld_xfrag(const void* xr, int bf, size_t row, int col) {
    if (bf) {
        return *(const bh8*)((const unsigned short*)xr + row * 128 + col);
    } else {
        const float* xp = (const float*)xr + row * 128 + col;
        float4 a = *(const float4*)xp;
        float4 b = *(const float4*)(xp + 4);
        bh8 r;
        r[0] = (short)f2b(a.x); r[1] = (short)f2b(a.y);
        r[2] = (short)f2b(a.z); r[3] = (short)f2b(a.w);
        r[4] = (short)f2b(b.x); r[5] = (short)f2b(b.y);
        r[6] = (short)f2b(b.z); r[7] = (short)f2b(b.w);
        return r;
    }
}

// ---------- K1: prep (self-detect) + detect->flags + zero padded counts + state ----------
// blocks [0,32): Wt1 | [32,48): Wt2 | [48]: detect flags | [49,49+NZ): zero counts
// last block: zero scan state
__global__ void k_prep2(const void* __restrict__ W1, unsigned short* __restrict__ Wt1,
                        const void* __restrict__ W2, unsigned short* __restrict__ Wt2,
                        const unsigned short* __restrict__ xs, const int* __restrict__ ei32,
                        int* __restrict__ flags, int* __restrict__ counts,
                        int* __restrict__ done, int N, int NZ) {
    int blk = blockIdx.x, t = threadIdx.x;
    if (blk < 48) {
        // self-detect bf16-vs-f32 (same heuristic as detect block)
        __shared__ int bad;
        if (t == 0) bad = 0;
        __syncthreads();
        int b = 0;
        for (int i = t; i < 4096; i += 256) {
            unsigned e = (xs[i] >> 7) & 0xFF;
            if (e >= 0xE2) b = 1;
        }
        if (b) atomicOr(&bad, 1);
        __syncthreads();
        int bf = bad ? 0 : 1;
        if (blk < 32) {
            int idx = blk * 512 + t * 2;
            #pragma unroll
            for (int j = 0; j < 2; j++, idx++) {      // Wt1[n][k] = W1[k][n], 128x128
                int k = idx >> 7, nn = idx & 127;
                Wt1[nn * 128 + k] = bf ? ((const unsigned short*)W1)[idx]
                                       : f2b(((const float*)W1)[idx]);
            }
        } else {
            int idx = (blk - 32) * 512 + t * 2;
            #pragma unroll
            for (int j = 0; j < 2; j++, idx++) {      // Wt2[n][k] = W2[k][n], k<128,n<64
                int k = idx >> 6, nn = idx & 63;
                Wt2[nn * 128 + k] = bf ? ((const unsigned short*)W2)[idx]
                                       : f2b(((const float*)W2)[idx]);
            }
        }
        return;
    }
    if (blk == 48) {                                   // flags for downstream kernels
        __shared__ int bad, nz;
        if (t == 0) { bad = 0; nz = 0; }
        __syncthreads();
        int b = 0;
        for (int i = t; i < 4096; i += 256) {
            unsigned e = (xs[i] >> 7) & 0xFF;
            if (e >= 0xE2) b = 1;
        }
        if (b) atomicOr(&bad, 1);
        int n = 0;
        for (int i = t; i < 512; i += 256) {
            if (ei32[2 * i + 1] != 0) n = 1;
        }
        if (n) atomicOr(&nz, 1);
        __syncthreads();
        if (t == 0) { flags[0] = bad ? 0 : 1; flags[1] = nz ? 0 : 1; }
        return;
    }
    int zb = blk - 49;
    if (zb < NZ) {                                     // zero padded counts (N*CPAD ints)
        int NT = N * CPAD;
        int base = zb * 1024 + t * 4;
        #pragma unroll
        for (int j = 0; j < 4; j++)
            if (base + j < NT) counts[base + j] = 0;
        return;
    }
    if (t == 0) done[0] = 0;                           // zero scan state
}

// ---------- K2: hist grid-stride (blocks < HB2)  ||  layer-1 GEMM (R5 shape) ----------
// hist: HEPT edges/thread, pipelined atomics. GEMM: W in LDS (36KB -> 4 blocks/CU),
// X fragments direct from global, epilogue direct from fp32 acc (2 fewer barriers).
__global__ __launch_bounds__(256)
void k_hist_gemm1(const int* __restrict__ ei, int* __restrict__ counts,
                  int* __restrict__ eoff,
                  const void* __restrict__ xr, const unsigned short* __restrict__ Wt,
                  const void* __restrict__ aSr, const void* __restrict__ aDr,
                  unsigned int* __restrict__ xh1b, float* __restrict__ a_src,
                  float* __restrict__ a_dst, const int* __restrict__ flags,
                  int E, int Et, int HB2, int N) {
    __shared__ unsigned short Wl[128 * 136];   // +8 pad: 2-way bank alias (free)
    __shared__ float aSf[128], aDf[128];
    if ((int)blockIdx.x < HB2) {              // -------- histogram path --------
        int i64f = flags[1];
        int ebase = blockIdx.x * (256 * HEPT) + threadIdx.x;
        #pragma unroll
        for (int j = 0; j < HEPT; j++) {
            int e = ebase + j * 256;
            if (e < Et) {
                int d = (e < E) ? ldi(ei, (size_t)E + e, i64f) : (e - E);
                eoff[e] = atomicAdd(&counts[(size_t)d * CPAD], 1);
            }
        }
        return;
    }
    // -------- GEMM path: D' = Wt1 x^T --------
    int t = threadIdx.x;
    int bf = flags[0];
    int r0 = ((int)blockIdx.x - HB2) * 64;
    if (t < 128) { aSf[t] = ldf(aSr, t, bf); aDf[t] = ldf(aDr, t, bf); }
    #pragma unroll
    for (int i = 0; i < 8; i++) {             // Wt1: 2048 uint4, coalesced stage
        int idx = t + 256 * i;
        int row = idx >> 4, c16 = idx & 15;
        *(uint4*)&Wl[row * 136 + c16 * 8] = ((const uint4*)Wt)[idx];
    }
    __syncthreads();
    int w = t >> 6, lane = t & 63;
    int m16 = lane & 15, quad = lane >> 4;
    int node = r0 + w * 16 + m16;
    bool valid = node < N;
    f32x4 acc[8];
    #pragma unroll
    for (int ct = 0; ct < 8; ct++) acc[ct] = (f32x4){0.f, 0.f, 0.f, 0.f};
    #pragma unroll
    for (int kb = 0; kb < 4; kb++) {
        int col = kb * 32 + quad * 8;
        bh8 xf = valid ? ld_xfrag(xr, bf, (size_t)node, col) : zero8();
        #pragma unroll
        for (int ct = 0; ct < 8; ct++) {
            bh8 wf = *(const bh8*)&Wl[(ct * 16 + m16) * 136 + col];
            acc[ct] = __builtin_amdgcn_mfma_f32_16x16x32_bf16(wf, xf, acc[ct], 0, 0, 0);
        }
    }
    // epilogue from acc: ch = ct*16 + quad*4 + r, head h == ct (16 ch/head)
    #pragma unroll
    for (int ct = 0; ct < 8; ct++) {
        float s = 0.f, d = 0.f;
        #pragma unroll
        for (int r = 0; r < 4; r++) {
            int ch = ct * 16 + quad * 4 + r;
            s += acc[ct][r] * aSf[ch];
            d += acc[ct][r] * aDf[ch];
        }
        s += __shfl_xor(s, 16); s += __shfl_xor(s, 32);
        d += __shfl_xor(d, 16); d += __shfl_xor(d, 32);
        if (valid) {
            if (quad == 0) {
                a_src[(size_t)node * 8 + ct] = s;
                a_dst[(size_t)node * 8 + ct] = d;
            }
            uint2 pk;
            pk.x = (unsigned int)f2b(acc[ct][0]) | ((unsigned int)f2b(acc[ct][1]) << 16);
            pk.y = (unsigned int)f2b(acc[ct][2]) | ((unsigned int)f2b(acc[ct][3]) << 16);
            *(uint2*)&xh1b[(size_t)node * 64 + ct * 8 + quad * 2] = pk;
        }
    }
}

// ---------- K3: single-pass scan over padded counts ----------
__global__ __launch_bounds__(256)
void k_scan(const int* __restrict__ counts, int* __restrict__ rowptr,
            int* __restrict__ bsums, int* __restrict__ done,
            int N, int Et, int NB) {
    __shared__ int sd[256];
    int t = threadIdx.x, b = blockIdx.x;
    int base = b * 1024 + t * 4;
    int v0 = (base + 0 < N) ? counts[(size_t)(base + 0) * CPAD] : 0;
    int v1 = (base + 1 < N) ? counts[(size_t)(base + 1) * CPAD] : 0;
    int v2 = (base + 2 < N) ? counts[(size_t)(base + 2) * CPAD] : 0;
    int v3 = (base + 3 < N) ? counts[(size_t)(base + 3) * CPAD] : 0;
    int ls = v0 + v1 + v2 + v3;
    sd[t] = ls; __syncthreads();
    for (int off = 1; off < 256; off <<= 1) {
        int x = 0;
        if (t >= off) x = sd[t - off];
        __syncthreads();
        if (t >= off) sd[t] += x;
        __syncthreads();
    }
    int incl = sd[t];
    int ex = incl - ls;
    if (t == 255) {                            // publish block total, bump done
        bsums[b] = incl;
        __threadfence();
        atomicAdd(done, 1);
    }
    if (t == 0) {                              // wait for all publishers
        while (atomicAdd(done, 0) < NB) __builtin_amdgcn_s_sleep(1);
    }
    __syncthreads();
    __threadfence();
    int contrib = (t < b) ? atomicAdd(&bsums[t], 0) : 0;   // parallel lookback reads
    sd[t] = contrib; __syncthreads();
    for (int o = 128; o > 0; o >>= 1) {        // tree-reduce predecessors' totals
        if (t < o) sd[t] += sd[t + o];
        __syncthreads();
    }
    int off2 = sd[0];
    if (base + 0 < N) rowptr[base + 0] = ex + off2; ex += v0;
    if (base + 1 < N) rowptr[base + 1] = ex + off2; ex += v1;
    if (base + 2 < N) rowptr[base + 2] = ex + off2; ex += v2;
    if (base + 3 < N) rowptr[base + 3] = ex + off2;
    if (b == NB - 1 && t == 255) rowptr[N] = Et;
}

// ---------- scatter (atomic-free, grid-stride HEPT for pipelined chains) ----------
__global__ void k_scatter(const int* __restrict__ ei, const int* __restrict__ rowptr,
                          const int* __restrict__ eoff, int* __restrict__ esrc,
                          const int* __restrict__ flags, int E, int Et) {
    int i64f = flags[1];
    int ebase = blockIdx.x * (256 * HEPT) + threadIdx.x;
    #pragma unroll
    for (int j = 0; j < HEPT; j++) {
        int e = ebase + j * 256;
        if (e < Et) {
            int s, d;
            if (e < E) { s = ldi(ei, (size_t)e, i64f); d = ldi(ei, (size_t)E + e, i64f); }
            else       { s = d = e - E; }
            esrc[rowptr[d] + eoff[e]] = s;
        }
    }
}

// ---------- layer 1 softmax-aggregate: 2 nodes/wave, setup chains hoisted ----------
// Node k=1's rowptr->esrc->a_src dependent chain issues before node k=0's loop runs,
// hiding ~1500cy of setup latency (same mechanism as HEPT hist ILP, across nodes).
__global__ __launch_bounds__(256)
void k_agg1(const int* __restrict__ rowptr, const int* __restrict__ esrc,
            const float* __restrict__ a_src, const float* __restrict__ a_dst,
            const unsigned int* __restrict__ xh1b, const void* __restrict__ b1,
            unsigned int* __restrict__ h1b, const int* __restrict__ flags, int N) {
    int pair = blockIdx.x * 4 + (threadIdx.x >> 6);
    int lane = threadIdx.x & 63;
    int bf = flags[0];
    int h8 = lane & 7;
    int q  = lane >> 3;
    float bia0 = ldf(b1, 2 * lane, bf);
    float bia1 = ldf(b1, 2 * lane + 1, bf);
    int   R0[2], R1[2], SN[2];
    float AD[2], AN[2];
    #pragma unroll
    for (int k = 0; k < 2; k++) {              // hoisted: rowptr + a_dst for both
        int node = pair * 2 + k;
        bool v = node < N;
        R0[k] = v ? rowptr[node] : 0;
        R1[k] = v ? rowptr[node + 1] : 0;
        AD[k] = v ? a_dst[(size_t)node * 8 + h8] : 0.f;
    }
    #pragma unroll
    for (int k = 0; k < 2; k++) {              // hoisted: first esrc + a_src for both
        int pidx = R0[k] + q;
        bool pval = pidx < R1[k];
        int s = pval ? esrc[pidx] : 0;
        SN[k] = s;
        AN[k] = pval ? a_src[(size_t)s * 8 + h8] : 0.f;
    }
    #pragma unroll
    for (int k = 0; k < 2; k++) {
        int node = pair * 2 + k;
        if (node >= N) continue;               // wave-uniform
        int r0 = R0[k], r1 = R1[k];
        float adst = AD[k];
        int   s_next = SN[k];
        float a_next = AN[k];
        float den = 0.f, acc0 = 0.f, acc1 = 0.f;
        for (int e = r0; e < r1; e += 8) {
            int   s_mine = s_next;
            float a_cur  = a_next;
            bool  vcur   = (e + q) < r1;
            int idx2 = e + 8 + q;
            bool v2 = idx2 < r1;
            s_next = v2 ? esrc[idx2] : 0;
            a_next = v2 ? a_src[(size_t)s_next * 8 + h8] : 0.f;
            float v = a_cur + adst;
            v = v > 0.f ? v : 0.2f * v;
            float ex = vcur ? __expf(v) : 0.f;
            den += ex;
            #pragma unroll
            for (int q2 = 0; q2 < 8; q2++) {
                int   s_q  = __builtin_amdgcn_readlane(s_mine, q2 * 8);
                float ex_q = __shfl(ex, q2 * 8 + q);
                const unsigned int* rowp = xh1b + (size_t)s_q * 64;
                unsigned int wv = rowp[lane];
                acc0 += ex_q * b2f((unsigned short)wv);
                acc1 += ex_q * b2f((unsigned short)(wv >> 16));
            }
        }
        den += __shfl_xor(den, 8);
        den += __shfl_xor(den, 16);
        den += __shfl_xor(den, 32);
        float dA = __shfl(den, q) + 1e-16f;
        float o0 = acc0 / dA + bia0;
        float o1 = acc1 / dA + bia1;
        o0 = o0 > 0.f ? o0 : expm1f(o0);
        o1 = o1 > 0.f ? o1 : expm1f(o1);
        h1b[(size_t)node * 64 + lane] =
            (unsigned int)f2b(o0) | ((unsigned int)f2b(o1) << 16);
    }
}

// ---------- layer 2 GEMM, MFMA: xh2 = h1 @ W2 via D' = Wt2 h1^T; fused att2 ----------
__global__ __launch_bounds__(256)
void k_gemm2m(const unsigned int* __restrict__ h1b, const unsigned short* __restrict__ Wt2,
              const void* __restrict__ aSr, const void* __restrict__ aDr,
              unsigned int* __restrict__ xh2b, float* __restrict__ a_src,
              float* __restrict__ a_dst, const int* __restrict__ flags, int N) {
    __shared__ unsigned short Xl[64 * 136];
    __shared__ unsigned short Wl[64 * 136];
    __shared__ float aSf[64], aDf[64];
    int t = threadIdx.x;
    int bf = flags[0];
    int r0 = blockIdx.x * 64;
    if (t < 64) { aSf[t] = ldf(aSr, t, bf); aDf[t] = ldf(aDr, t, bf); }
    #pragma unroll
    for (int i = 0; i < 4; i++) {            // Wt2: 64 rows x 16 uint4 = 1024 uint4
        int idx = t + 256 * i;
        int row = idx >> 4, c16 = idx & 15;
        *(uint4*)&Wl[row * 136 + c16 * 8] = ((const uint4*)Wt2)[idx];
    }
    {
        const uint4* Xv = (const uint4*)h1b;  // bf16 rows, 16 uint4 each
        #pragma unroll
        for (int i = 0; i < 4; i++) {
            int idx = t + 256 * i;
            int row = idx >> 4, c16 = idx & 15;
            uint4 v = (r0 + row < N) ? Xv[(size_t)(r0 + row) * 16 + c16] : uint4{0,0,0,0};
            *(uint4*)&Xl[row * 136 + c16 * 8] = v;
        }
    }
    __syncthreads();
    int w = t >> 6, lane = t & 63;
    int m16 = lane & 15, quad = lane >> 4;
    f32x4 acc[4];
    #pragma unroll
    for (int ct = 0; ct < 4; ct++) acc[ct] = (f32x4){0.f, 0.f, 0.f, 0.f};
    #pragma unroll
    for (int kb = 0; kb < 4; kb++) {
        bh8 xf = *(const bh8*)&Xl[(w * 16 + m16) * 136 + kb * 32 + quad * 8];
        #pragma unroll
        for (int ct = 0; ct < 4; ct++) {
            bh8 wf = *(const bh8*)&Wl[(ct * 16 + m16) * 136 + kb * 32 + quad * 8];
            acc[ct] = __builtin_amdgcn_mfma_f32_16x16x32_bf16(wf, xf, acc[ct], 0, 0, 0);
        }
    }
    float ps = 0.f, pd = 0.f;
    #pragma unroll
    for (int ct = 0; ct < 4; ct++) {
        #pragma unroll
        for (int r = 0; r < 4; r++) {
            int ch = ct * 16 + quad * 4 + r;
            ps += acc[ct][r] * aSf[ch];
            pd += acc[ct][r] * aDf[ch];
        }
    }
    ps += __shfl_xor(ps, 16); ps += __shfl_xor(ps, 32);
    pd += __shfl_xor(pd, 16); pd += __shfl_xor(pd, 32);
    int node = r0 + w * 16 + m16;
    if (node < N) {
        if (quad == 0) { a_src[node] = ps; a_dst[node] = pd; }
        #pragma unroll
        for (int ct = 0; ct < 4; ct++) {
            uint2 pk;
            pk.x = (unsigned int)f2b(acc[ct][0]) | ((unsigned int)f2b(acc[ct][1]) << 16);
            pk.y = (unsigned int)f2b(acc[ct][2]) | ((unsigned int)f2b(acc[ct][3]) << 16);
            *(uint2*)&xh2b[(size_t)node * 32 + ct * 8 + quad * 2] = pk;
        }
    }
}

// ---------- layer 2 softmax-aggregate -> output: 2 nodes/wave, hoisted setup ----------
__global__ __launch_bounds__(256)
void k_agg2(const int* __restrict__ rowptr, const int* __restrict__ esrc,
            const float* __restrict__ a_src, const float* __restrict__ a_dst,
            const unsigned int* __restrict__ xh2b, const void* __restrict__ bias,
            void* __restrict__ out, const int* __restrict__ flags, int N) {
    int pair = blockIdx.x * 4 + (threadIdx.x >> 6);
    int lane = threadIdx.x & 63;
    int bf = flags[0];
    int q = lane >> 3;
    const unsigned short* xs = (const unsigned short*)xh2b;
    float bia = ldf(bias, lane, bf);
    int   R0[2], R1[2], SN[2];
    float AD[2], AN[2];
    #pragma unroll
    for (int k = 0; k < 2; k++) {              // hoisted: rowptr + a_dst for both
        int node = pair * 2 + k;
        bool v = node < N;
        R0[k] = v ? rowptr[node] : 0;
        R1[k] = v ? rowptr[node + 1] : 0;
        AD[k] = v ? a_dst[node] : 0.f;
    }
    #pragma unroll
    for (int k = 0; k < 2; k++) {              // hoisted: first esrc + a_src for both
        int pidx = R0[k] + q;
        bool pval = pidx < R1[k];
        int s = pval ? esrc[pidx] : 0;
        SN[k] = s;
        AN[k] = pval ? a_src[s] : 0.f;
    }
    #pragma unroll
    for (int k = 0; k < 2; k++) {
        int node = pair * 2 + k;
        if (node >= N) continue;               // wave-uniform
        int r0 = R0[k], r1 = R1[k];
        float adst = AD[k];
        int   s_next = SN[k];
        float a_next = AN[k];
        float den = 0.f, acc = 0.f;
        for (int e = r0; e < r1; e += 8) {
            int   s_mine = s_next;
            float a_cur  = a_next;
            bool  vcur   = (e + q) < r1;
            int idx2 = e + 8 + q;
            bool v2 = idx2 < r1;
            s_next = v2 ? esrc[idx2] : 0;
            a_next = v2 ? a_src[s_next] : 0.f;
            float v = a_cur + adst;
            v = v > 0.f ? v : 0.2f * v;
            float ex = vcur ? __expf(v) : 0.f;
            den += ex;
            #pragma unroll
            for (int q2 = 0; q2 < 8; q2++) {
                int   s_q  = __builtin_amdgcn_readlane(s_mine, q2 * 8);
                float ex_q = __uint_as_float(
                    (unsigned int)__builtin_amdgcn_readlane(__float_as_uint(ex), q2 * 8));
                const unsigned short* rowp = xs + (size_t)s_q * 64;
                acc += ex_q * b2f(rowp[lane]);
            }
        }
        den += __shfl_xor(den, 8);
        den += __shfl_xor(den, 16);
        den += __shfl_xor(den, 32);
        float o = acc / (den + 1e-16f) + bia;
        size_t oi = (size_t)node * 64 + lane;
        if (bf) ((unsigned short*)out)[oi] = f2b(o);
        else    ((float*)out)[oi] = o;
    }
}

// ---------- launch ----------
extern "C" void kernel_launch(void* const* d_in, const int* in_sizes, int n_in,
                              void* d_out, int out_size, void* d_ws, size_t ws_size,
                              hipStream_t stream) {
    const void* x   = d_in[0];
    const int*  ei  = (const int*)d_in[1];
    const void* W1  = d_in[2];
    const void* aS1 = d_in[3];
    const void* aD1 = d_in[4];
    const void* b1  = d_in[5];
    const void* W2  = d_in[6];
    const void* aS2 = d_in[7];
    const void* aD2 = d_in[8];
    const void* b2v = d_in[9];

    const int N  = in_sizes[0] / 128;   // 50000
    const int E  = in_sizes[1] / 2;     // 800000
    const int Et = E + N;

    char* p = (char*)d_ws;
    auto alloc = [&](size_t bytes) -> char* {
        char* q = p; p += (bytes + 255) & ~(size_t)255; return q;
    };
    unsigned int* xh1b = (unsigned int*)alloc((size_t)N * 64 * 4);
    unsigned int* h1b  = (unsigned int*)alloc((size_t)N * 64 * 4);
    unsigned int* xh2b = (unsigned int*)alloc((size_t)N * 32 * 4);
    float* as1  = (float*)alloc((size_t)N * 8 * 4);
    float* ad1  = (float*)alloc((size_t)N * 8 * 4);
    float* as2  = (float*)alloc((size_t)N * 4);
    float* ad2  = (float*)alloc((size_t)N * 4);
    int* counts = (int*)alloc((size_t)N * CPAD * 4);   // padded: 1 counter / 64B line
    int* rowptr = (int*)alloc((size_t)(N + 1) * 4);
    int* eoff   = (int*)alloc((size_t)Et * 4);
    int* esrc   = (int*)alloc((size_t)Et * 4);
    int* bsums  = (int*)alloc(256 * 4);
    int* flags  = (int*)alloc(16 * 4);
    int* done   = (int*)alloc(16 * 4);
    unsigned short* Wt1 = (unsigned short*)alloc(128 * 128 * 2);
    unsigned short* Wt2 = (unsigned short*)alloc(64 * 128 * 2);

    const int NZ  = (N * CPAD + 1023) / 1024; // zero blocks for padded counts
    const int NB  = (N + 1023) / 1024;        // scan blocks (<=256 assumed)
    const int HB2 = (Et + 256 * HEPT - 1) / (256 * HEPT);  // hist/scatter blocks
    const int GT  = (N + 63) / 64;            // gemm1 tiles
    const int AB  = (N + 7) / 8;              // agg blocks (4 waves x 2 nodes)

    // K1: W transposes + flags + zero padded counts + zero scan state
    k_prep2<<<48 + 1 + NZ + 1, 256, 0, stream>>>(W1, Wt1, W2, Wt2,
                                                 (const unsigned short*)x, ei,
                                                 flags, counts, done, N, NZ);
    // K2: histogram (grid-stride, pipelined atomics) || layer-1 GEMM (36KB LDS)
    k_hist_gemm1<<<HB2 + GT, 256, 0, stream>>>(ei, counts, eoff, x, Wt1, aS1, aD1,
                                               xh1b, as1, ad1, flags, E, Et, HB2, N);
    // K3: single-pass scan -> final rowptr
    k_scan<<<NB, 256, 0, stream>>>(counts, rowptr, bsums, done, N, Et, NB);
    // K4: scatter edges into CSR (grid-stride, pipelined chains)
    k_scatter<<<HB2, 256, 0, stream>>>(ei, rowptr, eoff, esrc, flags, E, Et);
    // K5-K7: aggregate / GEMM2 / aggregate (agg: 2 nodes/wave, hoisted setup)
    k_agg1<<<AB, 256, 0, stream>>>(rowptr, esrc, as1, ad1, xh1b, b1, h1b, flags, N);
    k_gemm2m<<<GT, 256, 0, stream>>>(h1b, Wt2, aS2, aD2, xh2b, as2, ad2, flags, N);
    k_agg2<<<AB, 256, 0, stream>>>(rowptr, esrc, as2, ad2, xh2b, b2v, d_out, flags, N);
}